// Round 1
// baseline (421.208 us; speedup 1.0000x reference)
//
#include <hip/hip_runtime.h>

// Problem constants (B,S,D)=(2,2048,1024), H=16, DH=64, WINDOW=128
#define SQ      2048
#define NB      2
#define NH      16
#define DHD     64
#define WIN     128
#define DMODEL  1024
#define TRIPLE  3072

typedef __attribute__((ext_vector_type(8))) short  short8;
typedef __attribute__((ext_vector_type(4))) float  f32x4;

__device__ __forceinline__ unsigned short f2bf(float f) {
  unsigned u = __float_as_uint(f);
  u += 0x7fff + ((u >> 16) & 1);   // RNE
  return (unsigned short)(u >> 16);
}

// ---------------------------------------------------------------- cast fp32 -> bf16
__global__ void cast_bf16_kernel(const float* __restrict__ in,
                                 unsigned short* __restrict__ out, int n4) {
  int idx = blockIdx.x * blockDim.x + threadIdx.x;
  if (idx >= n4) return;
  f32x4 v = ((const f32x4*)in)[idx];
  ushort4 o;
  o.x = f2bf(v[0]); o.y = f2bf(v[1]); o.z = f2bf(v[2]); o.w = f2bf(v[3]);
  ((ushort4*)out)[idx] = o;
}

// ------------------------------------------------- transpose + cast: in[K][N] fp32 -> out[N][K] bf16
__global__ void transpose_cast_kernel(const float* __restrict__ in,
                                      unsigned short* __restrict__ out,
                                      int K, int N) {
  __shared__ float tile[32][33];
  int n0 = blockIdx.x * 32, k0 = blockIdx.y * 32;
  int tx = threadIdx.x, ty = threadIdx.y;       // 32 x 8
#pragma unroll
  for (int r = 0; r < 4; ++r)
    tile[ty + 8 * r][tx] = in[(size_t)(k0 + ty + 8 * r) * N + (n0 + tx)];
  __syncthreads();
#pragma unroll
  for (int r = 0; r < 4; ++r)
    out[(size_t)(n0 + ty + 8 * r) * K + (k0 + tx)] = f2bf(tile[tx][ty + 8 * r]);
}

// ------------------------------------------------- C[M][N] fp32 = A[M][K]bf16 * Bt[N][K]bf16^T
// 128x128 tile, BK=64, 256 threads = 4 waves, each wave a 64x64 subtile (4x4 MFMA 16x16x32)
#define LDP 72   // LDS row stride in shorts (64 + 8 pad: breaks frag-read bank grouping)
__global__ __launch_bounds__(256) void gemm_bt_kernel(
    const unsigned short* __restrict__ A,
    const unsigned short* __restrict__ Bt,
    float* __restrict__ C,
    int M, int N, int K) {
  __shared__ short lsA[128 * LDP];
  __shared__ short lsB[128 * LDP];
  int tid  = threadIdx.x;
  int wave = tid >> 6, lane = tid & 63;
  int quad = lane >> 4, l16 = lane & 15;
  int wm = (wave >> 1) * 64, wn = (wave & 1) * 64;
  int m0 = blockIdx.x * 128, n0 = blockIdx.y * 128;

  int srow = tid >> 3;             // 0..31
  int scol = (tid & 7) * 8;        // 0..56

  f32x4 acc[4][4] = {};

  const short* Ag = (const short*)A;
  const short* Bg = (const short*)Bt;

  for (int k0 = 0; k0 < K; k0 += 64) {
#pragma unroll
    for (int c = 0; c < 4; ++c) {
      int r = srow + 32 * c;
      short8 va = *(const short8*)(Ag + (size_t)(m0 + r) * K + k0 + scol);
      *(short8*)(&lsA[r * LDP + scol]) = va;
      short8 vb = *(const short8*)(Bg + (size_t)(n0 + r) * K + k0 + scol);
      *(short8*)(&lsB[r * LDP + scol]) = vb;
    }
    __syncthreads();
#pragma unroll
    for (int ks = 0; ks < 2; ++ks) {
      short8 af[4], bf[4];
#pragma unroll
      for (int t = 0; t < 4; ++t) {
        af[t] = *(const short8*)(&lsA[(wm + t * 16 + l16) * LDP + ks * 32 + quad * 8]);
        bf[t] = *(const short8*)(&lsB[(wn + t * 16 + l16) * LDP + ks * 32 + quad * 8]);
      }
#pragma unroll
      for (int mt = 0; mt < 4; ++mt)
#pragma unroll
        for (int nt = 0; nt < 4; ++nt)
          acc[mt][nt] = __builtin_amdgcn_mfma_f32_16x16x32_bf16(
              af[mt], bf[nt], acc[mt][nt], 0, 0, 0);
    }
    __syncthreads();
  }
  // C/D layout: col = lane&15, row = quad*4 + reg
#pragma unroll
  for (int mt = 0; mt < 4; ++mt)
#pragma unroll
    for (int nt = 0; nt < 4; ++nt)
#pragma unroll
      for (int r = 0; r < 4; ++r) {
        int row = m0 + wm + mt * 16 + quad * 4 + r;
        int col = n0 + wn + nt * 16 + l16;
        C[(size_t)row * N + col] = acc[mt][nt][r];
      }
}

// ------------------------------------------------- local causal attention, fp32 VALU
// qkv fp32 [NB*SQ][3072] (q at +0, k at +1024, v at +2048, each h*64+dh)
// out bf16 [NB*SQ][1024]
// grid (SQ/64, NH, NB), block 64: lane = query within group of 64.
__global__ __launch_bounds__(64) void attn_kernel(
    const float* __restrict__ qkv, unsigned short* __restrict__ attnout) {
  int i0 = blockIdx.x * 64;
  int h  = blockIdx.y;
  int b  = blockIdx.z;
  int lane = threadIdx.x;
  int i = i0 + lane;

  const float* base = qkv + (size_t)b * SQ * TRIPLE;

  // q row (pre-scaled by 1/sqrt(DH))
  float q[DHD];
  {
    const float* qrow = base + (size_t)i * TRIPLE + h * DHD;
#pragma unroll
    for (int d4 = 0; d4 < DHD / 4; ++d4) {
      f32x4 v = *(const f32x4*)(qrow + 4 * d4);
      q[4 * d4 + 0] = v[0] * 0.125f;
      q[4 * d4 + 1] = v[1] * 0.125f;
      q[4 * d4 + 2] = v[2] * 0.125f;
      q[4 * d4 + 3] = v[3] * 0.125f;
    }
  }

  float o[DHD];
#pragma unroll
  for (int d = 0; d < DHD; ++d) o[d] = 0.f;
  float m = -1e30f, l = 0.f;

  // j union for queries [i0, i0+63]: [i0-128+1, i0+63]; loop 12 chunks of 16 from i0-128
  for (int cc = 0; cc < 12; ++cc) {
    int jc = i0 - WIN + cc * 16;
    float s[16];
#pragma unroll
    for (int c = 0; c < 16; ++c) {
      int j = jc + c;
      float a0 = 0.f, a1 = 0.f, a2 = 0.f, a3 = 0.f;
      if (j >= 0) {  // uniform branch
        const float* krow = base + (size_t)j * TRIPLE + DMODEL + h * DHD;
#pragma unroll
        for (int d = 0; d < DHD / 4; ++d) {
          a0 += q[4 * d + 0] * krow[4 * d + 0];
          a1 += q[4 * d + 1] * krow[4 * d + 1];
          a2 += q[4 * d + 2] * krow[4 * d + 2];
          a3 += q[4 * d + 3] * krow[4 * d + 3];
        }
      }
      bool ok = (j >= 0) && (j <= i) && (j > i - WIN);
      s[c] = ok ? ((a0 + a1) + (a2 + a3)) : -1e30f;
    }
    float cm = s[0];
#pragma unroll
    for (int c = 1; c < 16; ++c) cm = fmaxf(cm, s[c]);
    float mnew  = fmaxf(m, cm);
    float alpha = __expf(m - mnew);       // exp(0)=1 when both -1e30: safe
    l *= alpha;
#pragma unroll
    for (int d = 0; d < DHD; ++d) o[d] *= alpha;
    float p[16];
#pragma unroll
    for (int c = 0; c < 16; ++c) {
      p[c] = (s[c] > -1e29f) ? __expf(s[c] - mnew) : 0.f;  // explicit zero for masked
      l += p[c];
    }
    m = mnew;
#pragma unroll
    for (int c = 0; c < 16; ++c) {
      int j = jc + c;
      if (j >= 0) {  // uniform branch
        const float* vrow = base + (size_t)j * TRIPLE + 2 * DMODEL + h * DHD;
#pragma unroll
        for (int d = 0; d < DHD; ++d) o[d] += p[c] * vrow[d];
      }
    }
  }

  float inv = 1.0f / l;
  unsigned short* orow = attnout + (size_t)(b * SQ + i) * DMODEL + h * DHD;
#pragma unroll
  for (int d8 = 0; d8 < DHD / 8; ++d8) {
    short8 v;
#pragma unroll
    for (int e = 0; e < 8; ++e) v[e] = (short)f2bf(o[d8 * 8 + e] * inv);
    *(short8*)(orow + d8 * 8) = v;
  }
}

// ----------------------------------------------------------------------------------
extern "C" void kernel_launch(void* const* d_in, const int* in_sizes, int n_in,
                              void* d_out, int out_size, void* d_ws, size_t ws_size,
                              hipStream_t stream) {
  const float* x     = (const float*)d_in[0];   // [2,2048,1024]
  const float* w_qkv = (const float*)d_in[1];   // [1024,3072]
  const float* w_out = (const float*)d_in[2];   // [1024,1024]
  float* out = (float*)d_out;                   // [2,2048,1024] fp32

  char* ws = (char*)d_ws;
  // workspace layout (72 MB total)
  unsigned short* xb    = (unsigned short*)(ws);               //  8 MB  [4096][1024] bf16
  unsigned short* wqkvT = (unsigned short*)(ws + 8388608);     //  6 MB  [3072][1024] bf16
  unsigned short* woutT = (unsigned short*)(ws + 14680064);    //  2 MB  [1024][1024] bf16
  float*          qkv   = (float*)(ws + 16777216);             // 48 MB  [4096][3072] fp32
  unsigned short* attn  = (unsigned short*)(ws + 67108864);    //  8 MB  [4096][1024] bf16

  // 1. cast x to bf16
  cast_bf16_kernel<<<4096, 256, 0, stream>>>(x, xb, (NB * SQ * DMODEL) / 4);
  // 2. transpose+cast weights: [K][N] -> [N][K]
  dim3 tb(32, 8);
  transpose_cast_kernel<<<dim3(TRIPLE / 32, DMODEL / 32), tb, 0, stream>>>(w_qkv, wqkvT, DMODEL, TRIPLE);
  transpose_cast_kernel<<<dim3(DMODEL / 32, DMODEL / 32), tb, 0, stream>>>(w_out, woutT, DMODEL, DMODEL);
  // 3. qkv = xb @ wqkvT^T   (fp32 out)
  gemm_bt_kernel<<<dim3((NB * SQ) / 128, TRIPLE / 128), 256, 0, stream>>>(
      xb, wqkvT, qkv, NB * SQ, TRIPLE, DMODEL);
  // 4. attention
  attn_kernel<<<dim3(SQ / 64, NH, NB), 64, 0, stream>>>(qkv, attn);
  // 5. out = attn @ woutT^T
  gemm_bt_kernel<<<dim3((NB * SQ) / 128, DMODEL / 128), 256, 0, stream>>>(
      attn, woutT, out, NB * SQ, DMODEL, DMODEL);
}

// Round 2
// 348.260 us; speedup vs baseline: 1.2095x; 1.2095x over previous
//
#include <hip/hip_runtime.h>

// Problem constants (B,S,D)=(2,2048,1024), H=16, DH=64, WINDOW=128
#define SQ      2048
#define NB      2
#define NH      16
#define DHD     64
#define WIN     128
#define DMODEL  1024
#define TRIPLE  3072

typedef __attribute__((ext_vector_type(8))) short  short8;
typedef __attribute__((ext_vector_type(4))) float  f32x4;

__device__ __forceinline__ unsigned short f2bf(float f) {
  unsigned u = __float_as_uint(f);
  u += 0x7fff + ((u >> 16) & 1);   // RNE
  return (unsigned short)(u >> 16);
}

// ---------------------------------------------------------------- cast fp32 -> bf16
__global__ void cast_bf16_kernel(const float* __restrict__ in,
                                 unsigned short* __restrict__ out, int n4) {
  int idx = blockIdx.x * blockDim.x + threadIdx.x;
  if (idx >= n4) return;
  f32x4 v = ((const f32x4*)in)[idx];
  ushort4 o;
  o.x = f2bf(v[0]); o.y = f2bf(v[1]); o.z = f2bf(v[2]); o.w = f2bf(v[3]);
  ((ushort4*)out)[idx] = o;
}

// ------------------------------------------------- transpose + cast: in[K][N] fp32 -> out[N][K] bf16
__global__ void transpose_cast_kernel(const float* __restrict__ in,
                                      unsigned short* __restrict__ out,
                                      int K, int N) {
  __shared__ float tile[32][33];
  int n0 = blockIdx.x * 32, k0 = blockIdx.y * 32;
  int tx = threadIdx.x, ty = threadIdx.y;       // 32 x 8
#pragma unroll
  for (int r = 0; r < 4; ++r)
    tile[ty + 8 * r][tx] = in[(size_t)(k0 + ty + 8 * r) * N + (n0 + tx)];
  __syncthreads();
#pragma unroll
  for (int r = 0; r < 4; ++r)
    out[(size_t)(n0 + ty + 8 * r) * K + (k0 + tx)] = f2bf(tile[tx][ty + 8 * r]);
}

// ------------------------------------------------- C[M][N] fp32 = A[M][K]bf16 * Bt[N][K]bf16^T
// 128x128 tile, BK=64, 256 threads = 4 waves, each wave a 64x64 subtile (4x4 MFMA 16x16x32)
#define LDP 72   // LDS row stride in shorts (64 + 8 pad: breaks frag-read bank grouping)
__global__ __launch_bounds__(256) void gemm_bt_kernel(
    const unsigned short* __restrict__ A,
    const unsigned short* __restrict__ Bt,
    float* __restrict__ C,
    int M, int N, int K) {
  __shared__ short lsA[128 * LDP];
  __shared__ short lsB[128 * LDP];
  int tid  = threadIdx.x;
  int wave = tid >> 6, lane = tid & 63;
  int quad = lane >> 4, l16 = lane & 15;
  int wm = (wave >> 1) * 64, wn = (wave & 1) * 64;
  int m0 = blockIdx.x * 128, n0 = blockIdx.y * 128;

  int srow = tid >> 3;             // 0..31
  int scol = (tid & 7) * 8;        // 0..56

  f32x4 acc[4][4] = {};

  const short* Ag = (const short*)A;
  const short* Bg = (const short*)Bt;

  for (int k0 = 0; k0 < K; k0 += 64) {
#pragma unroll
    for (int c = 0; c < 4; ++c) {
      int r = srow + 32 * c;
      short8 va = *(const short8*)(Ag + (size_t)(m0 + r) * K + k0 + scol);
      *(short8*)(&lsA[r * LDP + scol]) = va;
      short8 vb = *(const short8*)(Bg + (size_t)(n0 + r) * K + k0 + scol);
      *(short8*)(&lsB[r * LDP + scol]) = vb;
    }
    __syncthreads();
#pragma unroll
    for (int ks = 0; ks < 2; ++ks) {
      short8 af[4], bf[4];
#pragma unroll
      for (int t = 0; t < 4; ++t) {
        af[t] = *(const short8*)(&lsA[(wm + t * 16 + l16) * LDP + ks * 32 + quad * 8]);
        bf[t] = *(const short8*)(&lsB[(wn + t * 16 + l16) * LDP + ks * 32 + quad * 8]);
      }
#pragma unroll
      for (int mt = 0; mt < 4; ++mt)
#pragma unroll
        for (int nt = 0; nt < 4; ++nt)
          acc[mt][nt] = __builtin_amdgcn_mfma_f32_16x16x32_bf16(
              af[mt], bf[nt], acc[mt][nt], 0, 0, 0);
    }
    __syncthreads();
  }
  // C/D layout: col = lane&15, row = quad*4 + reg
#pragma unroll
  for (int mt = 0; mt < 4; ++mt)
#pragma unroll
    for (int nt = 0; nt < 4; ++nt)
#pragma unroll
      for (int r = 0; r < 4; ++r) {
        int row = m0 + wm + mt * 16 + quad * 4 + r;
        int col = n0 + wn + nt * 16 + l16;
        C[(size_t)row * N + col] = acc[mt][nt][r];
      }
}

// ------------------------------------------------- local causal attention, fp32 VALU
// qkv fp32 [NB*SQ][3072] (q at +0, k at +1024, v at +2048, each h*64+dh)
// out bf16 [NB*SQ][1024]
// grid (SQ/64, NH, NB), block 256 = 4 waves over the SAME 64 queries (lane = query).
// j-union for the 64-query group: 12 chunks of 16; wave w computes chunks 3w..3w+2,
// partial (m,l,o) merged across waves via pairwise LDS tree.
__global__ __launch_bounds__(256) void attn_kernel(
    const float* __restrict__ qkv, unsigned short* __restrict__ attnout) {
  __shared__ float so[2][64][68];     // 68-stride: 16B-aligned rows, bounded bank aliasing
  __shared__ float sml[2][2][64];

  int i0 = blockIdx.x * 64;
  int h  = blockIdx.y;
  int b  = blockIdx.z;
  int wave = threadIdx.x >> 6;
  int lane = threadIdx.x & 63;
  int i = i0 + lane;

  const float* base = qkv + (size_t)b * SQ * TRIPLE;

  // q row (pre-scaled by 1/sqrt(DH))
  float q[DHD];
  {
    const float* qrow = base + (size_t)i * TRIPLE + h * DHD;
#pragma unroll
    for (int d4 = 0; d4 < DHD / 4; ++d4) {
      f32x4 v = *(const f32x4*)(qrow + 4 * d4);
      q[4 * d4 + 0] = v[0] * 0.125f;
      q[4 * d4 + 1] = v[1] * 0.125f;
      q[4 * d4 + 2] = v[2] * 0.125f;
      q[4 * d4 + 3] = v[3] * 0.125f;
    }
  }

  float o[DHD];
#pragma unroll
  for (int d = 0; d < DHD; ++d) o[d] = 0.f;
  float m = -1e30f, l = 0.f;

  // wave w handles chunks 3w .. 3w+2 (48 j-values of the 192-wide union)
  for (int cc = 3 * wave; cc < 3 * wave + 3; ++cc) {
    int jc = i0 - WIN + cc * 16;
    float s[16];
#pragma unroll
    for (int c = 0; c < 16; ++c) {
      int j = jc + c;
      float a0 = 0.f, a1 = 0.f, a2 = 0.f, a3 = 0.f;
      if (j >= 0) {  // uniform branch
        const float* krow = base + (size_t)j * TRIPLE + DMODEL + h * DHD;
#pragma unroll
        for (int d = 0; d < DHD / 4; ++d) {
          a0 += q[4 * d + 0] * krow[4 * d + 0];
          a1 += q[4 * d + 1] * krow[4 * d + 1];
          a2 += q[4 * d + 2] * krow[4 * d + 2];
          a3 += q[4 * d + 3] * krow[4 * d + 3];
        }
      }
      bool ok = (j >= 0) && (j <= i) && (j > i - WIN);
      s[c] = ok ? ((a0 + a1) + (a2 + a3)) : -1e30f;
    }
    float cm = s[0];
#pragma unroll
    for (int c = 1; c < 16; ++c) cm = fmaxf(cm, s[c]);
    float mnew  = fmaxf(m, cm);
    float alpha = __expf(m - mnew);       // exp(0)=1 when both -1e30: safe
    l *= alpha;
#pragma unroll
    for (int d = 0; d < DHD; ++d) o[d] *= alpha;
    float p[16];
#pragma unroll
    for (int c = 0; c < 16; ++c) {
      p[c] = (s[c] > -1e29f) ? __expf(s[c] - mnew) : 0.f;  // explicit zero for masked
      l += p[c];
    }
    m = mnew;
#pragma unroll
    for (int c = 0; c < 16; ++c) {
      int j = jc + c;
      if (j >= 0) {  // uniform branch
        const float* vrow = base + (size_t)j * TRIPLE + 2 * DMODEL + h * DHD;
#pragma unroll
        for (int d = 0; d < DHD; ++d) o[d] += p[c] * vrow[d];
      }
    }
  }

  // ---- pairwise merge tree: (1->0, 3->2) then (2->0) ----
  // publish helper pattern: slot s gets (m,l,o) of the publishing wave
  if (wave & 1) {                         // waves 1,3 publish to slots 0,1
    int slot = wave >> 1;
#pragma unroll
    for (int d4 = 0; d4 < DHD / 4; ++d4)
      *(f32x4*)(&so[slot][lane][4 * d4]) = *(f32x4*)(&o[4 * d4]);
    sml[slot][0][lane] = m;
    sml[slot][1][lane] = l;
  }
  __syncthreads();
  if (!(wave & 1)) {                      // waves 0,2 merge slots 0,1
    int slot = wave >> 1;
    float m2 = sml[slot][0][lane], l2 = sml[slot][1][lane];
    float mn = fmaxf(m, m2);
    float a1 = __expf(m - mn), a2 = __expf(m2 - mn);
    l = a1 * l + a2 * l2;
#pragma unroll
    for (int d = 0; d < DHD; ++d) o[d] = a1 * o[d] + a2 * so[slot][lane][d];
    m = mn;
  }
  __syncthreads();
  if (wave == 2) {                        // wave 2 publishes to slot 0
#pragma unroll
    for (int d4 = 0; d4 < DHD / 4; ++d4)
      *(f32x4*)(&so[0][lane][4 * d4]) = *(f32x4*)(&o[4 * d4]);
    sml[0][0][lane] = m;
    sml[0][1][lane] = l;
  }
  __syncthreads();
  if (wave == 0) {                        // wave 0 final merge + store
    float m2 = sml[0][0][lane], l2 = sml[0][1][lane];
    float mn = fmaxf(m, m2);
    float a1 = __expf(m - mn), a2 = __expf(m2 - mn);
    l = a1 * l + a2 * l2;
#pragma unroll
    for (int d = 0; d < DHD; ++d) o[d] = a1 * o[d] + a2 * so[0][lane][d];

    float inv = 1.0f / l;
    unsigned short* orow = attnout + (size_t)(b * SQ + i) * DMODEL + h * DHD;
#pragma unroll
    for (int d8 = 0; d8 < DHD / 8; ++d8) {
      short8 v;
#pragma unroll
      for (int e = 0; e < 8; ++e) v[e] = (short)f2bf(o[d8 * 8 + e] * inv);
      *(short8*)(orow + d8 * 8) = v;
    }
  }
}

// ----------------------------------------------------------------------------------
extern "C" void kernel_launch(void* const* d_in, const int* in_sizes, int n_in,
                              void* d_out, int out_size, void* d_ws, size_t ws_size,
                              hipStream_t stream) {
  const float* x     = (const float*)d_in[0];   // [2,2048,1024]
  const float* w_qkv = (const float*)d_in[1];   // [1024,3072]
  const float* w_out = (const float*)d_in[2];   // [1024,1024]
  float* out = (float*)d_out;                   // [2,2048,1024] fp32

  char* ws = (char*)d_ws;
  // workspace layout (72 MB total)
  unsigned short* xb    = (unsigned short*)(ws);               //  8 MB  [4096][1024] bf16
  unsigned short* wqkvT = (unsigned short*)(ws + 8388608);     //  6 MB  [3072][1024] bf16
  unsigned short* woutT = (unsigned short*)(ws + 14680064);    //  2 MB  [1024][1024] bf16
  float*          qkv   = (float*)(ws + 16777216);             // 48 MB  [4096][3072] fp32
  unsigned short* attn  = (unsigned short*)(ws + 67108864);    //  8 MB  [4096][1024] bf16

  // 1. cast x to bf16
  cast_bf16_kernel<<<4096, 256, 0, stream>>>(x, xb, (NB * SQ * DMODEL) / 4);
  // 2. transpose+cast weights: [K][N] -> [N][K]
  dim3 tb(32, 8);
  transpose_cast_kernel<<<dim3(TRIPLE / 32, DMODEL / 32), tb, 0, stream>>>(w_qkv, wqkvT, DMODEL, TRIPLE);
  transpose_cast_kernel<<<dim3(DMODEL / 32, DMODEL / 32), tb, 0, stream>>>(w_out, woutT, DMODEL, DMODEL);
  // 3. qkv = xb @ wqkvT^T   (fp32 out)
  gemm_bt_kernel<<<dim3((NB * SQ) / 128, TRIPLE / 128), 256, 0, stream>>>(
      xb, wqkvT, qkv, NB * SQ, TRIPLE, DMODEL);
  // 4. attention (4 waves/query-group, j-split + LDS merge tree)
  attn_kernel<<<dim3(SQ / 64, NH, NB), 256, 0, stream>>>(qkv, attn);
  // 5. out = attn @ woutT^T
  gemm_bt_kernel<<<dim3((NB * SQ) / 128, DMODEL / 128), 256, 0, stream>>>(
      attn, woutT, out, NB * SQ, DMODEL, DMODEL);
}

// Round 3
// 171.285 us; speedup vs baseline: 2.4591x; 2.0332x over previous
//
#include <hip/hip_runtime.h>

// Problem constants (B,S,D)=(2,2048,1024), H=16, DH=64, WINDOW=128
#define SQ      2048
#define NB      2
#define NH      16
#define DHD     64
#define WIN     128
#define DMODEL  1024
#define TRIPLE  3072

typedef __attribute__((ext_vector_type(8))) short  short8;
typedef __attribute__((ext_vector_type(4))) float  f32x4;

__device__ __forceinline__ unsigned short f2bf(float f) {
  unsigned u = __float_as_uint(f);
  u += 0x7fff + ((u >> 16) & 1);   // RNE
  return (unsigned short)(u >> 16);
}

// ---------------------------------------------------------------- cast fp32 -> bf16
__global__ void cast_bf16_kernel(const float* __restrict__ in,
                                 unsigned short* __restrict__ out, int n4) {
  int idx = blockIdx.x * blockDim.x + threadIdx.x;
  if (idx >= n4) return;
  f32x4 v = ((const f32x4*)in)[idx];
  ushort4 o;
  o.x = f2bf(v[0]); o.y = f2bf(v[1]); o.z = f2bf(v[2]); o.w = f2bf(v[3]);
  ((ushort4*)out)[idx] = o;
}

// ------------------------------------------------- transpose + cast: in[K][N] fp32 -> out[N][K] bf16
__global__ void transpose_cast_kernel(const float* __restrict__ in,
                                      unsigned short* __restrict__ out,
                                      int K, int N) {
  __shared__ float tile[32][33];
  int n0 = blockIdx.x * 32, k0 = blockIdx.y * 32;
  int tx = threadIdx.x, ty = threadIdx.y;       // 32 x 8
#pragma unroll
  for (int r = 0; r < 4; ++r)
    tile[ty + 8 * r][tx] = in[(size_t)(k0 + ty + 8 * r) * N + (n0 + tx)];
  __syncthreads();
#pragma unroll
  for (int r = 0; r < 4; ++r)
    out[(size_t)(n0 + ty + 8 * r) * K + (k0 + tx)] = f2bf(tile[tx][ty + 8 * r]);
}

// ------------------------------------------------- C[M][N] = A[M][K]bf16 * Bt[N][K]bf16^T
// 128x128 tile, BK=64, 256 threads = 4 waves, each wave a 64x64 subtile (4x4 MFMA 16x16x32)
// BF16OUT: write C as bf16 (u16), else fp32.
#define LDP 72   // LDS row stride in shorts
template <bool BF16OUT>
__global__ __launch_bounds__(256) void gemm_bt_kernel(
    const unsigned short* __restrict__ A,
    const unsigned short* __restrict__ Bt,
    void* __restrict__ Cv,
    int M, int N, int K) {
  __shared__ short lsA[128 * LDP];
  __shared__ short lsB[128 * LDP];
  int tid  = threadIdx.x;
  int wave = tid >> 6, lane = tid & 63;
  int quad = lane >> 4, l16 = lane & 15;
  int wm = (wave >> 1) * 64, wn = (wave & 1) * 64;
  int m0 = blockIdx.x * 128, n0 = blockIdx.y * 128;

  int srow = tid >> 3;             // 0..31
  int scol = (tid & 7) * 8;        // 0..56

  f32x4 acc[4][4] = {};

  const short* Ag = (const short*)A;
  const short* Bg = (const short*)Bt;

  for (int k0 = 0; k0 < K; k0 += 64) {
#pragma unroll
    for (int c = 0; c < 4; ++c) {
      int r = srow + 32 * c;
      short8 va = *(const short8*)(Ag + (size_t)(m0 + r) * K + k0 + scol);
      *(short8*)(&lsA[r * LDP + scol]) = va;
      short8 vb = *(const short8*)(Bg + (size_t)(n0 + r) * K + k0 + scol);
      *(short8*)(&lsB[r * LDP + scol]) = vb;
    }
    __syncthreads();
#pragma unroll
    for (int ks = 0; ks < 2; ++ks) {
      short8 af[4], bf[4];
#pragma unroll
      for (int t = 0; t < 4; ++t) {
        af[t] = *(const short8*)(&lsA[(wm + t * 16 + l16) * LDP + ks * 32 + quad * 8]);
        bf[t] = *(const short8*)(&lsB[(wn + t * 16 + l16) * LDP + ks * 32 + quad * 8]);
      }
#pragma unroll
      for (int mt = 0; mt < 4; ++mt)
#pragma unroll
        for (int nt = 0; nt < 4; ++nt)
          acc[mt][nt] = __builtin_amdgcn_mfma_f32_16x16x32_bf16(
              af[mt], bf[nt], acc[mt][nt], 0, 0, 0);
    }
    __syncthreads();
  }
  // C/D layout: col = lane&15, row = quad*4 + reg
#pragma unroll
  for (int mt = 0; mt < 4; ++mt)
#pragma unroll
    for (int nt = 0; nt < 4; ++nt)
#pragma unroll
      for (int r = 0; r < 4; ++r) {
        int row = m0 + wm + mt * 16 + quad * 4 + r;
        int col = n0 + wn + nt * 16 + l16;
        if (BF16OUT)
          ((unsigned short*)Cv)[(size_t)row * N + col] = f2bf(acc[mt][nt][r]);
        else
          ((float*)Cv)[(size_t)row * N + col] = acc[mt][nt][r];
      }
}

// ------------------------------------------------- MFMA flash attention (bf16 in/out)
// qkvb bf16 [NB*SQ][3072] (q +0, k +1024, v +2048; per head h*64+d)
// block = 256 thr / 4 waves per (64-query group, head, b); wave w owns 16 queries.
// 6 chunks of 32 keys, cooperative double-buffered LDS staging (K row-major, V transposed).
#define KSTR 72   // K tile row stride (shorts)
#define VSTR 40   // V^T tile row stride (shorts)
#define PSTR 36   // P tile row stride (shorts)
__global__ __launch_bounds__(256) void attn_kernel(
    const unsigned short* __restrict__ qkvb,
    unsigned short* __restrict__ attnout) {
  __shared__ short Kl[2][32 * KSTR];
  __shared__ short Vt[2][64 * VSTR];
  __shared__ short Pl[4][16 * PSTR];

  int i0 = blockIdx.x * 64, h = blockIdx.y, b = blockIdx.z;
  int tid = threadIdx.x, wave = tid >> 6, lane = tid & 63;
  int quad = lane >> 4, l16 = lane & 15;
  const unsigned short* base = qkvb + (size_t)b * SQ * TRIPLE;

  // Q A-frags (A[m=lane&15][k=quad*8+e]), held across the whole loop
  short8 qa[2];
  {
    int qi = i0 + wave * 16 + l16;
    const unsigned short* qrow = base + (size_t)qi * TRIPLE + h * DHD;
    qa[0] = *(const short8*)(qrow + quad * 8);
    qa[1] = *(const short8*)(qrow + 32 + quad * 8);
  }

  f32x4 o[4] = {};
  float mrow[4] = {-1e30f, -1e30f, -1e30f, -1e30f};
  float lrow[4] = {0.f, 0.f, 0.f, 0.f};

  int cstart = (i0 >= WIN) ? 0 : ((WIN - i0) >> 5);
  int nch = 6 - cstart;
  int jc0 = i0 - WIN + cstart * 32;   // >= 0 by construction

  int srow_ = tid >> 3;               // 0..31 (staging row)
  int scol_ = (tid & 7) * 8;          // 0..56 (staging col)

  // ---- stage chunk c into buffer bb (all 256 threads) ----
  auto stage = [&](int c, int bb) {
    int j = jc0 + c * 32 + srow_;
    const unsigned short* kr = base + (size_t)j * TRIPLE + DMODEL + h * DHD + scol_;
    *(short8*)(&Kl[bb][srow_ * KSTR + scol_]) = *(const short8*)kr;
    const unsigned short* vr = base + (size_t)j * TRIPLE + 2 * DMODEL + h * DHD + scol_;
    short8 vv = *(const short8*)vr;
#pragma unroll
    for (int e = 0; e < 8; ++e)
      Vt[bb][(scol_ + e) * VSTR + srow_] = vv[e];
  };

  stage(0, 0);
  __syncthreads();

  int irow = i0 + wave * 16 + quad * 4;   // + r = query index of acc row r

  for (int c = 0; c < nch; ++c) {
    int bb = c & 1;
    if (c + 1 < nch) stage(c + 1, bb ^ 1);
    int jc = jc0 + c * 32;

    // ---- S = Q * K^T (C-layout: row=quad*4+r, col=lane&15) ----
    f32x4 s[2] = {};
#pragma unroll
    for (int ks = 0; ks < 2; ++ks) {
#pragma unroll
      for (int nt = 0; nt < 2; ++nt) {
        short8 bk = *(const short8*)(&Kl[bb][(nt * 16 + l16) * KSTR + ks * 32 + quad * 8]);
        s[nt] = __builtin_amdgcn_mfma_f32_16x16x32_bf16(qa[ks], bk, s[nt], 0, 0, 0);
      }
    }
    // ---- scale + window mask ----
#pragma unroll
    for (int nt = 0; nt < 2; ++nt)
#pragma unroll
      for (int r = 0; r < 4; ++r) {
        int i_ = irow + r;
        int j_ = jc + nt * 16 + l16;
        bool ok = (j_ <= i_) && (j_ > i_ - WIN);
        s[nt][r] = ok ? s[nt][r] * 0.125f : -1e30f;
      }
    // ---- online softmax (row-wise over 32 cols: 2 tiles x 16 lanes) ----
    float rm[4];
#pragma unroll
    for (int r = 0; r < 4; ++r) rm[r] = fmaxf(s[0][r], s[1][r]);
#pragma unroll
    for (int off = 1; off < 16; off <<= 1)
#pragma unroll
      for (int r = 0; r < 4; ++r) rm[r] = fmaxf(rm[r], __shfl_xor(rm[r], off, 64));
    float al[4];
#pragma unroll
    for (int r = 0; r < 4; ++r) {
      float mn = fmaxf(mrow[r], rm[r]);
      al[r] = __expf(mrow[r] - mn);
      mrow[r] = mn;
    }
    f32x4 p[2];
#pragma unroll
    for (int nt = 0; nt < 2; ++nt)
#pragma unroll
      for (int r = 0; r < 4; ++r) p[nt][r] = __expf(s[nt][r] - mrow[r]);
    float rs[4];
#pragma unroll
    for (int r = 0; r < 4; ++r) rs[r] = p[0][r] + p[1][r];
#pragma unroll
    for (int off = 1; off < 16; off <<= 1)
#pragma unroll
      for (int r = 0; r < 4; ++r) rs[r] += __shfl_xor(rs[r], off, 64);
#pragma unroll
    for (int r = 0; r < 4; ++r) lrow[r] = lrow[r] * al[r] + rs[r];
#pragma unroll
    for (int nt = 0; nt < 4; ++nt)
#pragma unroll
      for (int r = 0; r < 4; ++r) o[nt][r] *= al[r];
    // ---- P: C-layout -> LDS -> A-frag (per-wave private; DS in-order per wave) ----
#pragma unroll
    for (int nt = 0; nt < 2; ++nt)
#pragma unroll
      for (int r = 0; r < 4; ++r)
        Pl[wave][(quad * 4 + r) * PSTR + nt * 16 + l16] = f2bf(p[nt][r]);
    short8 pa = *(const short8*)(&Pl[wave][l16 * PSTR + quad * 8]);
    // ---- O += P * V  (V^T staged: B-frag = Vt[d=nt*16+l16][j=quad*8+e]) ----
#pragma unroll
    for (int nt = 0; nt < 4; ++nt) {
      short8 bv = *(const short8*)(&Vt[bb][(nt * 16 + l16) * VSTR + quad * 8]);
      o[nt] = __builtin_amdgcn_mfma_f32_16x16x32_bf16(pa, bv, o[nt], 0, 0, 0);
    }
    __syncthreads();
  }

  // ---- epilogue ----
  float inv[4];
#pragma unroll
  for (int r = 0; r < 4; ++r) inv[r] = 1.0f / lrow[r];
#pragma unroll
  for (int nt = 0; nt < 4; ++nt)
#pragma unroll
    for (int r = 0; r < 4; ++r) {
      int i_ = irow + r;
      int d_ = nt * 16 + l16;
      attnout[(size_t)(b * SQ + i_) * DMODEL + h * DHD + d_] = f2bf(o[nt][r] * inv[r]);
    }
}

// ----------------------------------------------------------------------------------
extern "C" void kernel_launch(void* const* d_in, const int* in_sizes, int n_in,
                              void* d_out, int out_size, void* d_ws, size_t ws_size,
                              hipStream_t stream) {
  const float* x     = (const float*)d_in[0];   // [2,2048,1024]
  const float* w_qkv = (const float*)d_in[1];   // [1024,3072]
  const float* w_out = (const float*)d_in[2];   // [1024,1024]
  float* out = (float*)d_out;                   // [2,2048,1024] fp32

  char* ws = (char*)d_ws;
  // workspace layout (48 MB total)
  unsigned short* xb    = (unsigned short*)(ws);               //  8 MB  [4096][1024] bf16
  unsigned short* wqkvT = (unsigned short*)(ws + 8388608);     //  6 MB  [3072][1024] bf16
  unsigned short* woutT = (unsigned short*)(ws + 14680064);    //  2 MB  [1024][1024] bf16
  unsigned short* qkvb  = (unsigned short*)(ws + 16777216);    // 24 MB  [4096][3072] bf16
  unsigned short* attn  = (unsigned short*)(ws + 41943040);    //  8 MB  [4096][1024] bf16

  // 1. cast x to bf16
  cast_bf16_kernel<<<4096, 256, 0, stream>>>(x, xb, (NB * SQ * DMODEL) / 4);
  // 2. transpose+cast weights: [K][N] -> [N][K]
  dim3 tb(32, 8);
  transpose_cast_kernel<<<dim3(TRIPLE / 32, DMODEL / 32), tb, 0, stream>>>(w_qkv, wqkvT, DMODEL, TRIPLE);
  transpose_cast_kernel<<<dim3(DMODEL / 32, DMODEL / 32), tb, 0, stream>>>(w_out, woutT, DMODEL, DMODEL);
  // 3. qkvb = xb @ wqkvT^T   (bf16 out)
  gemm_bt_kernel<true><<<dim3((NB * SQ) / 128, TRIPLE / 128), 256, 0, stream>>>(
      xb, wqkvT, qkvb, NB * SQ, TRIPLE, DMODEL);
  // 4. MFMA flash attention
  attn_kernel<<<dim3(SQ / 64, NH, NB), 256, 0, stream>>>(qkvb, attn);
  // 5. out = attn @ woutT^T  (fp32 out)
  gemm_bt_kernel<false><<<dim3((NB * SQ) / 128, DMODEL / 128), 256, 0, stream>>>(
      attn, woutT, out, NB * SQ, DMODEL, DMODEL);
}